// Round 6
// baseline (284.681 us; speedup 1.0000x reference)
//
#include <hip/hip_runtime.h>
#include <stdint.h>

#define NN 2048
#define FF 128
#define ALPHA 0.2f

typedef unsigned short u16;
typedef __attribute__((ext_vector_type(8))) short bf16x8;  // 8 bf16 in 4 VGPRs
typedef __attribute__((ext_vector_type(4))) float f32x4;

__device__ __forceinline__ float bf2f(u16 h) {
    union { uint32_t u; float f; } v; v.u = ((uint32_t)h) << 16; return v.f;
}
__device__ __forceinline__ u16 f2bf(float x) {
    union { float f; uint32_t u; } v; v.f = x;
    uint32_t r = v.u + 0x7fffu + ((v.u >> 16) & 1u);  // RNE
    return (u16)(r >> 16);
}
__device__ __forceinline__ uint4 pack8(const float o[8]) {
    uint4 r;
    r.x = (uint32_t)f2bf(o[0]) | ((uint32_t)f2bf(o[1]) << 16);
    r.y = (uint32_t)f2bf(o[2]) | ((uint32_t)f2bf(o[3]) << 16);
    r.z = (uint32_t)f2bf(o[4]) | ((uint32_t)f2bf(o[5]) << 16);
    r.w = (uint32_t)f2bf(o[6]) | ((uint32_t)f2bf(o[7]) << 16);
    return r;
}
__device__ __forceinline__ void load8f(const float* p, size_t i, float o[8]) {
    float4 a = *(const float4*)(p + i);
    float4 b = *(const float4*)(p + i + 4);
    o[0]=a.x; o[1]=a.y; o[2]=a.z; o[3]=a.w;
    o[4]=b.x; o[5]=b.y; o[6]=b.z; o[7]=b.w;
}

// ---------------------------------------------------------------------------
// Fused GAT, fp32 in / FP32 OUT, zero workspace.
// Block = (batch b, 64-row i-tile); 256 threads = 4 waves.
// Scores: src_i = x_i·(W^T a_src), dst_j = x_j·(W^T a_dst), fp32-exact.
// j-loop: stage x_j (bf16) -> Xs; h_j = x_j·W^T via MFMA; relayout -> Hs[o][j];
// P = adj ? exp(lrelu(src_i+dst_j)) : 0 -> Ps bf16 (denominator sums the SAME
// bf16-rounded p); acc += Ps·Hs via MFMA. Epilogue: ELU(acc/l) -> fp32 out.
// ---------------------------------------------------------------------------
__global__ __launch_bounds__(256) void k_gat(
    const float* __restrict__ x,     // [B][N][F]
    const int*   __restrict__ adj,   // [B][N][N]
    const float* __restrict__ w,     // [F][F] (o-major)
    const float* __restrict__ as_,   // [F]
    const float* __restrict__ ad_,   // [F]
    float* __restrict__ out)         // [B][N][F] fp32
{
    __shared__ __attribute__((aligned(16))) u16 Ws[128][136];
    __shared__ __attribute__((aligned(16))) u16 Xs[64][136];
    __shared__ __attribute__((aligned(16))) u16 Hs[128][72];
    __shared__ __attribute__((aligned(16))) u16 Ps[64][72];
    __shared__ float aS[128], aD[128];
    __shared__ float waS[128], waD[128];
    __shared__ float srcL[64], dstL[64];
    __shared__ float lred[64][4];
    __shared__ float lrow[64];

    const int b  = blockIdx.x >> 5;
    const int i0 = (blockIdx.x & 31) * 64;
    const int t  = threadIdx.x;
    const int wv = t >> 6, lane = t & 63;
    const int quad = lane >> 4, lr = lane & 15;

    // ---- stage W (bf16) into LDS; a vectors into LDS
    {
        const int o = t >> 1, fb = (t & 1) * 64;
        #pragma unroll
        for (int k = 0; k < 8; ++k) {
            float v8[8];
            load8f(w, (size_t)o * FF + fb + k * 8, v8);
            *(uint4*)&Ws[o][fb + k * 8] = pack8(v8);
        }
    }
    if (t < 128) aS[t] = as_[t];
    else         aD[t - 128] = ad_[t - 128];
    __syncthreads();

    // ---- waS/waD = W^T a  (fp32-exact score path)
    if (t < 128) {
        float s = 0.f;
        for (int o = 0; o < FF; ++o) s += w[(size_t)o * FF + t] * aS[o];
        waS[t] = s;
    } else {
        const int f = t - 128;
        float s = 0.f;
        for (int o = 0; o < FF; ++o) s += w[(size_t)o * FF + f] * aD[o];
        waD[f] = s;
    }
    __syncthreads();

    // ---- src_i for this block's 64 rows
    {
        const int il = t >> 2, q = t & 3;
        float s = 0.f;
        #pragma unroll
        for (int k = 0; k < 4; ++k) {
            float v8[8];
            load8f(x, (size_t)(b * NN + i0 + il) * FF + q * 32 + k * 8, v8);
            #pragma unroll
            for (int u = 0; u < 8; ++u) s += v8[u] * waS[q * 32 + k * 8 + u];
        }
        lred[il][q] = s;
    }
    __syncthreads();
    if (t < 64) srcL[t] = lred[t][0] + lred[t][1] + lred[t][2] + lred[t][3];
    __syncthreads();

    const int il = t >> 2, q = t & 3;
    const float src_i = srcL[il];
    const int* adjrow = adj + (size_t)(b * NN + i0 + il) * NN;

    f32x4 acc[8] = {};
    float lacc = 0.f;

    for (int j0 = 0; j0 < NN; j0 += 64) {
        // (a) stage x j-tile (bf16) + dst_j partials
        {
            float dp = 0.f;
            const int fb = q * 32;
            #pragma unroll
            for (int k = 0; k < 4; ++k) {
                float v8[8];
                load8f(x, (size_t)(b * NN + j0 + il) * FF + fb + k * 8, v8);
                *(uint4*)&Xs[il][fb + k * 8] = pack8(v8);
                #pragma unroll
                for (int u = 0; u < 8; ++u) dp += v8[u] * waD[fb + k * 8 + u];
            }
            lred[il][q] = dp;
        }
        __syncthreads();   // (A) Xs + lred ready; prev-iter PV done with Hs/Ps
        if (t < 64) dstL[t] = lred[t][0] + lred[t][1] + lred[t][2] + lred[t][3];

        // (b) h_j = x_j · W^T  (MFMA; wave wv owns j-rows wv*16..+15)
        f32x4 hacc[8] = {};
        #pragma unroll
        for (int kc = 0; kc < 4; ++kc) {
            const int ko = kc * 32 + quad * 8;
            bf16x8 a = *(const bf16x8*)&Xs[wv * 16 + lr][ko];
            #pragma unroll
            for (int t8 = 0; t8 < 8; ++t8) {
                bf16x8 bb = *(const bf16x8*)&Ws[t8 * 16 + lr][ko];
                hacc[t8] = __builtin_amdgcn_mfma_f32_16x16x32_bf16(a, bb, hacc[t8], 0, 0, 0);
            }
        }
        // relayout: Hs[o][j_local]  (C/D: col=lr -> o, row=quad*4+reg -> j)
        #pragma unroll
        for (int t8 = 0; t8 < 8; ++t8) {
            #pragma unroll
            for (int reg = 0; reg < 4; ++reg)
                Hs[t8 * 16 + lr][wv * 16 + quad * 4 + reg] = f2bf(hacc[t8][reg]);
        }
        __syncthreads();   // (B) Hs + dstL visible

        // (c) P-gen: thread (il, q) covers j in [q*16, q*16+16)
        #pragma unroll
        for (int it = 0; it < 4; ++it) {
            const int jl = q * 16 + it * 4;
            int4 a4 = *(const int4*)(adjrow + j0 + jl);
            const int* ai = (const int*)&a4;
            u16 pb[4];
            #pragma unroll
            for (int u = 0; u < 4; ++u) {
                float e = src_i + dstL[jl + u];
                e = e > 0.f ? e : ALPHA * e;
                float p = __expf(e);
                p = (ai[u] > 0) ? p : 0.f;
                pb[u] = f2bf(p);
                lacc += bf2f(pb[u]);   // denominator == numerator's P exactly
            }
            uint2 pk;
            pk.x = (uint32_t)pb[0] | ((uint32_t)pb[1] << 16);
            pk.y = (uint32_t)pb[2] | ((uint32_t)pb[3] << 16);
            *(uint2*)&Ps[il][jl] = pk;
        }
        __syncthreads();   // (C) Ps visible

        // (d) PV: acc += Ps · Hs
        #pragma unroll
        for (int kc = 0; kc < 2; ++kc) {
            const int ko = kc * 32 + quad * 8;
            bf16x8 a = *(const bf16x8*)&Ps[wv * 16 + lr][ko];
            #pragma unroll
            for (int t8 = 0; t8 < 8; ++t8) {
                bf16x8 bb = *(const bf16x8*)&Hs[t8 * 16 + lr][ko];
                acc[t8] = __builtin_amdgcn_mfma_f32_16x16x32_bf16(a, bb, acc[t8], 0, 0, 0);
            }
        }
        // next iter's barrier (A) orders PV reads vs Xs/Hs/Ps overwrite
    }

    __syncthreads();
    lred[il][q] = lacc;
    __syncthreads();
    if (t < 64) lrow[t] = lred[t][0] + lred[t][1] + lred[t][2] + lred[t][3];
    __syncthreads();

    // ---- epilogue: normalize, ELU, FP32 store
    #pragma unroll
    for (int t8 = 0; t8 < 8; ++t8) {
        const int o = t8 * 16 + lr;
        #pragma unroll
        for (int reg = 0; reg < 4; ++reg) {
            const int rl = wv * 16 + quad * 4 + reg;
            const float l = fmaxf(lrow[rl], 1e-30f);
            float v = acc[t8][reg] / l;
            v = v > 0.f ? v : __expf(v) - 1.f;
            out[(size_t)(b * NN + i0 + rl) * FF + o] = v;
        }
    }
}

// ---------------------------------------------------------------------------
extern "C" void kernel_launch(void* const* d_in, const int* in_sizes, int n_in,
                              void* d_out, int out_size, void* d_ws, size_t ws_size,
                              hipStream_t stream) {
    // remap inputs by element count (robust to ordering; a_src before a_dst
    // per setup_inputs dict order)
    const float* x = nullptr; const int* adj = nullptr; const float* w = nullptr;
    const float* as_ = nullptr; const float* ad_ = nullptr;
    for (int i = 0; i < n_in; ++i) {
        const long long s = in_sizes[i];
        if      (s == (long long)8 * 2048 * 128)  x   = (const float*)d_in[i];
        else if (s == (long long)8 * 2048 * 2048) adj = (const int*)d_in[i];
        else if (s == 128 * 128)                  w   = (const float*)d_in[i];
        else if (s == 128) { if (!as_) as_ = (const float*)d_in[i]; else ad_ = (const float*)d_in[i]; }
    }
    if (!x)   x   = (const float*)d_in[0];
    if (!adj) adj = (const int*)d_in[1];
    if (!w)   w   = (const float*)d_in[2];
    if (!as_) as_ = (const float*)d_in[3];
    if (!ad_) ad_ = (const float*)d_in[4];
    float* out = (float*)d_out;

    (void)d_ws; (void)ws_size; (void)out_size;
    k_gat<<<256, 256, 0, stream>>>(x, adj, w, as_, ad_, out);
}

// Round 7
// 221.114 us; speedup vs baseline: 1.2875x; 1.2875x over previous
//
#include <hip/hip_runtime.h>
#include <stdint.h>

#define NB 8
#define NN 2048
#define FF 128
#define ALPHA 0.2f

typedef unsigned short u16;
typedef __attribute__((ext_vector_type(8))) short bf16x8;  // 8 bf16, 4 VGPRs
typedef __attribute__((ext_vector_type(4))) float f32x4;

__device__ __forceinline__ float bf2f(u16 h) {
    union { uint32_t u; float f; } v; v.u = ((uint32_t)h) << 16; return v.f;
}
__device__ __forceinline__ u16 f2bf(float x) {
    union { float f; uint32_t u; } v; v.f = x;
    uint32_t r = v.u + 0x7fffu + ((v.u >> 16) & 1u);  // RNE
    return (u16)(r >> 16);
}
__device__ __forceinline__ uint4 pack8(const float o[8]) {
    uint4 r;
    r.x = (uint32_t)f2bf(o[0]) | ((uint32_t)f2bf(o[1]) << 16);
    r.y = (uint32_t)f2bf(o[2]) | ((uint32_t)f2bf(o[3]) << 16);
    r.z = (uint32_t)f2bf(o[4]) | ((uint32_t)f2bf(o[5]) << 16);
    r.w = (uint32_t)f2bf(o[6]) | ((uint32_t)f2bf(o[7]) << 16);
    return r;
}
__device__ __forceinline__ void load8f(const float* p, size_t i, float o[8]) {
    float4 a = *(const float4*)(p + i);
    float4 b = *(const float4*)(p + i + 4);
    o[0]=a.x; o[1]=a.y; o[2]=a.z; o[3]=a.w;
    o[4]=b.x; o[5]=b.y; o[6]=b.z; o[7]=b.w;
}

// ---------------------------------------------------------------------------
// Kernel 1: prep. h = x·W^T via MFMA (bf16 in, fp32 acc) -> hT[b][o][n] bf16
// (coalesced via LDS bounce); src/dst = x·(W^T a) accumulated in fp32 during
// x staging (fp32-exact scores — R6-validated numerics).
// 256 blocks = 8 b x 32 n-tiles(64); 256 threads = 4 waves.
// ---------------------------------------------------------------------------
__global__ __launch_bounds__(256) void k_prep(
    const float* __restrict__ x,    // [B][N][F]
    const float* __restrict__ w,    // [F][F] o-major
    const float* __restrict__ as_,  // [F]
    const float* __restrict__ ad_,  // [F]
    u16* __restrict__ hT,           // [B][F][N] bf16
    float* __restrict__ srcp, float* __restrict__ dstp)
{
    __shared__ __attribute__((aligned(16))) u16 Ws[128][136];   // also bounce buf
    __shared__ __attribute__((aligned(16))) u16 Xs[64][136];
    __shared__ float waS[128], waD[128];
    __shared__ float lredS[64][4], lredD[64][4];

    const int b  = blockIdx.x >> 5;
    const int n0 = (blockIdx.x & 31) * 64;
    const int t  = threadIdx.x;
    const int wv = t >> 6, lane = t & 63, quad = lane >> 4, lr = lane & 15;

    // stage W (bf16)
    {
        const int o = t >> 1, fb = (t & 1) * 64;
        #pragma unroll
        for (int k = 0; k < 8; ++k) {
            float v8[8];
            load8f(w, (size_t)o * FF + fb + k * 8, v8);
            *(uint4*)&Ws[o][fb + k * 8] = pack8(v8);
        }
    }
    // waS/waD = W^T a (fp32, from global)
    if (t < 128) {
        float s = 0.f;
        for (int o = 0; o < FF; ++o) s += w[(size_t)o * FF + t] * as_[o];
        waS[t] = s;
    } else {
        const int f = t - 128;
        float s = 0.f;
        for (int o = 0; o < FF; ++o) s += w[(size_t)o * FF + f] * ad_[o];
        waD[f] = s;
    }
    __syncthreads();

    // stage x tile (bf16) + fp32 src/dst partials
    {
        const int r = t >> 2, q = t & 3;
        float sp = 0.f, dp = 0.f;
        #pragma unroll
        for (int k = 0; k < 4; ++k) {
            float v8[8];
            load8f(x, (size_t)(b * NN + n0 + r) * FF + q * 32 + k * 8, v8);
            *(uint4*)&Xs[r][q * 32 + k * 8] = pack8(v8);
            #pragma unroll
            for (int u = 0; u < 8; ++u) {
                sp += v8[u] * waS[q * 32 + k * 8 + u];
                dp += v8[u] * waD[q * 32 + k * 8 + u];
            }
        }
        lredS[r][q] = sp; lredD[r][q] = dp;
    }
    __syncthreads();
    if (t < 64) {
        srcp[b * NN + n0 + t] = lredS[t][0] + lredS[t][1] + lredS[t][2] + lredS[t][3];
        dstp[b * NN + n0 + t] = lredD[t][0] + lredD[t][1] + lredD[t][2] + lredD[t][3];
    }

    // h MFMA: wave wv owns n-rows wv*16..+15
    f32x4 hacc[8] = {};
    #pragma unroll
    for (int kc = 0; kc < 4; ++kc) {
        const int ko = kc * 32 + quad * 8;
        bf16x8 a = *(const bf16x8*)&Xs[wv * 16 + lr][ko];
        #pragma unroll
        for (int t8 = 0; t8 < 8; ++t8) {
            bf16x8 bb = *(const bf16x8*)&Ws[t8 * 16 + lr][ko];
            hacc[t8] = __builtin_amdgcn_mfma_f32_16x16x32_bf16(a, bb, hacc[t8], 0, 0, 0);
        }
    }
    __syncthreads();   // all MFMA LDS reads done; Ws reusable as bounce buffer

    // bounce acc -> HsB[o][nl] (stride 68), then coalesced copy to hT
    u16* HsB = &Ws[0][0];
    #pragma unroll
    for (int t8 = 0; t8 < 8; ++t8) {
        #pragma unroll
        for (int reg = 0; reg < 4; ++reg)
            HsB[(t8 * 16 + lr) * 68 + wv * 16 + quad * 4 + reg] = f2bf(hacc[t8][reg]);
    }
    __syncthreads();
    {
        const int r16 = t >> 4, ng = t & 15;
        #pragma unroll
        for (int s = 0; s < 8; ++s) {
            const int o = s * 16 + r16;
            uint2 v = *(const uint2*)&HsB[o * 68 + ng * 4];
            *(uint2*)&hT[(size_t)(b * FF + o) * NN + n0 + ng * 4] = v;
        }
    }
}

// ---------------------------------------------------------------------------
// Kernel 2: attention. 512 blocks = 8 b x 64 i-tiles(32); 256 threads = 4
// waves; ~45 KB LDS -> 2 blocks/CU. j-loop of 128 with 2 barriers/iter:
// stage hT tile -> Hs[o][jl]; P = adj ? exp(lrelu(src_i+dst_j)) : 0 -> Ps
// bf16 (denominator sums the same bf16-rounded p); PV: 16 MFMA/wave.
// Epilogue: ELU(acc/l) -> fp32 out.
// ---------------------------------------------------------------------------
__global__ __launch_bounds__(256) void k_attn(
    const int*   __restrict__ adj,   // [B][N][N]
    const u16*   __restrict__ hT,    // [B][F][N] bf16
    const float* __restrict__ srcp,
    const float* __restrict__ dstp,
    float* __restrict__ out)         // [B][N][F] fp32
{
    __shared__ __attribute__((aligned(16))) u16 Hs[128][136];
    __shared__ __attribute__((aligned(16))) u16 Ps[32][136];
    __shared__ float lred[32][8];
    __shared__ float lrow[32];

    const int b  = blockIdx.x >> 6;
    const int i0 = (blockIdx.x & 63) * 32;
    const int t  = threadIdx.x;
    const int wv = t >> 6, lane = t & 63, quad = lane >> 4, lr = lane & 15;
    const int rowt = (wv & 1) * 16, colt = (wv >> 1) * 64;

    const int il = t >> 3, q = t & 7;            // P-gen: row il, 16 j's at q*16
    const float src_i  = srcp[b * NN + i0 + il];
    const int*   adjrow = adj + (size_t)(b * NN + i0 + il) * NN;
    const float* dstb   = dstp + b * NN;

    const int r16 = t >> 4, c16 = t & 15;        // Hs staging mapping

    f32x4 acc[4] = {};
    float lacc = 0.f;

    for (int j0 = 0; j0 < NN; j0 += 128) {
        // stage Hs: 128 o-rows x 128 j (32 KB), coalesced 256 B runs
        #pragma unroll
        for (int s = 0; s < 8; ++s) {
            const int o = s * 16 + r16;
            uint4 v = *(const uint4*)(hT + (size_t)(b * FF + o) * NN + j0 + c16 * 8);
            *(uint4*)&Hs[o][c16 * 8] = v;
        }
        // P-gen: thread (il, q) covers j = q*16 .. q*16+16
        {
            int4   a4[4]; float4 d4[4];
            #pragma unroll
            for (int it = 0; it < 4; ++it) {
                a4[it] = *(const int4*)(adjrow + j0 + q * 16 + it * 4);
                d4[it] = *(const float4*)(dstb + j0 + q * 16 + it * 4);
            }
            u16 pb[16];
            #pragma unroll
            for (int it = 0; it < 4; ++it) {
                const int*   ai = (const int*)&a4[it];
                const float* dv = (const float*)&d4[it];
                #pragma unroll
                for (int u = 0; u < 4; ++u) {
                    float e = src_i + dv[u];
                    e = e > 0.f ? e : ALPHA * e;
                    float p = __expf(e);
                    p = (ai[u] > 0) ? p : 0.f;
                    const u16 pv = f2bf(p);
                    pb[it * 4 + u] = pv;
                    lacc += bf2f(pv);           // denom == numerator's P exactly
                }
            }
            uint4 w0, w1;
            w0.x = (uint32_t)pb[0]  | ((uint32_t)pb[1]  << 16);
            w0.y = (uint32_t)pb[2]  | ((uint32_t)pb[3]  << 16);
            w0.z = (uint32_t)pb[4]  | ((uint32_t)pb[5]  << 16);
            w0.w = (uint32_t)pb[6]  | ((uint32_t)pb[7]  << 16);
            w1.x = (uint32_t)pb[8]  | ((uint32_t)pb[9]  << 16);
            w1.y = (uint32_t)pb[10] | ((uint32_t)pb[11] << 16);
            w1.z = (uint32_t)pb[12] | ((uint32_t)pb[13] << 16);
            w1.w = (uint32_t)pb[14] | ((uint32_t)pb[15] << 16);
            *(uint4*)&Ps[il][q * 16]     = w0;
            *(uint4*)&Ps[il][q * 16 + 8] = w1;
        }
        __syncthreads();   // Hs + Ps visible

        // PV: wave (rowt, colt): acc += P[rowt..+16] · h[colt..+64]
        #pragma unroll
        for (int kc = 0; kc < 4; ++kc) {
            const int ko = kc * 32 + quad * 8;
            bf16x8 a = *(const bf16x8*)&Ps[rowt + lr][ko];
            #pragma unroll
            for (int t8 = 0; t8 < 4; ++t8) {
                bf16x8 bb = *(const bf16x8*)&Hs[colt + t8 * 16 + lr][ko];
                acc[t8] = __builtin_amdgcn_mfma_f32_16x16x32_bf16(a, bb, acc[t8], 0, 0, 0);
            }
        }
        __syncthreads();   // PV reads done before next overwrite
    }

    lred[il][q] = lacc;
    __syncthreads();
    if (t < 32) {
        float s = 0.f;
        #pragma unroll
        for (int k = 0; k < 8; ++k) s += lred[t][k];
        lrow[t] = s;
    }
    __syncthreads();

    // epilogue: normalize, ELU, fp32 store
    #pragma unroll
    for (int t8 = 0; t8 < 4; ++t8) {
        const int col = colt + t8 * 16 + lr;
        #pragma unroll
        for (int reg = 0; reg < 4; ++reg) {
            const int row = rowt + quad * 4 + reg;
            const float l = fmaxf(lrow[row], 1e-30f);
            float v = acc[t8][reg] / l;
            v = v > 0.f ? v : __expf(v) - 1.f;
            out[(size_t)(b * NN + i0 + row) * FF + col] = v;
        }
    }
}

// ---------------------------------------------------------------------------
extern "C" void kernel_launch(void* const* d_in, const int* in_sizes, int n_in,
                              void* d_out, int out_size, void* d_ws, size_t ws_size,
                              hipStream_t stream) {
    const float* x = nullptr; const int* adj = nullptr; const float* w = nullptr;
    const float* as_ = nullptr; const float* ad_ = nullptr;
    for (int i = 0; i < n_in; ++i) {
        const long long s = in_sizes[i];
        if      (s == (long long)NB * NN * FF)  x   = (const float*)d_in[i];
        else if (s == (long long)NB * NN * NN)  adj = (const int*)d_in[i];
        else if (s == FF * FF)                  w   = (const float*)d_in[i];
        else if (s == FF) { if (!as_) as_ = (const float*)d_in[i]; else ad_ = (const float*)d_in[i]; }
    }
    if (!x)   x   = (const float*)d_in[0];
    if (!adj) adj = (const int*)d_in[1];
    if (!w)   w   = (const float*)d_in[2];
    if (!as_) as_ = (const float*)d_in[3];
    if (!ad_) ad_ = (const float*)d_in[4];
    float* out = (float*)d_out;

    u16*   hT   = (u16*)d_ws;                              // 4 MiB
    float* srcp = (float*)((char*)d_ws + (size_t)NB * FF * NN * sizeof(u16));
    float* dstp = srcp + NB * NN;                          // 64 KiB each

    k_prep<<<256, 256, 0, stream>>>(x, w, as_, ad_, hT, srcp, dstp);
    k_attn<<<512, 256, 0, stream>>>(adj, hT, srcp, dstp, out);
}